// Round 17
// baseline (6926.776 us; speedup 1.0000x reference)
//
#include <hip/hip_runtime.h>

typedef unsigned int uint;
typedef unsigned short ushort;
typedef unsigned long long u64;
typedef __attribute__((ext_vector_type(8))) short s16x8;
typedef __attribute__((ext_vector_type(4))) float f32x4;
typedef __attribute__((ext_vector_type(4))) uint u32x4;

// problem dims (fixed)
#define SEQ 1024
#define BATCH 64
#define INDIM 512
#define HID 1024

// ---- workspace layout (bytes) ----
#define OFF_BUF   0ull
#define SZ_BUF    (65536ull * 1024ull * 2ull)           // c0 -> r0 (in-place), bf16
#define OFF_W0B   (OFF_BUF + SZ_BUF)                    // W_ih0 bf16 (1024x512)
#define OFF_WH0B  (OFF_W0B  + 1048576ull)               // W_hh0 bf16
#define OFF_W1B   (OFF_WH0B + 2097152ull)               // W_ih1 bf16
#define OFF_WH1B  (OFF_W1B  + 2097152ull)               // W_hh1 bf16
#define OFF_HINIT (OFF_WH1B + 2097152ull)               // hidden bf16 [2][64][1024]
#define OFF_HDB1  (OFF_HINIT + 262144ull)               // L1 h double buffer [2][64][1024]
#define OFF_FLG   (OFF_HDB1 + 262144ull)                // flag sets, 128B-padded slots
#define OFF_RING  (OFF_FLG + 131072ull)                 // c1 ring [4][16][16][16][64] f32 = 4MB
#define OFF_PPART (OFF_RING + 4194304ull)               // pooled partials [4][1024][1024] f32
#define WS_NEEDED (OFF_PPART + 16777216ull)

__device__ __forceinline__ ushort f2bf(float f) {
    uint u = __float_as_uint(f);
    uint r = (u + 0x7fffu + ((u >> 16) & 1u)) >> 16;
    return (ushort)r;
}
__device__ __forceinline__ float bf2f(ushort h) {
    return __uint_as_float(((uint)h) << 16);
}

// write-through stores (update IF; leave no dirty L2 lines) — R10-proven
__device__ __forceinline__ void stf32wt(float* p, float v) {
    asm volatile("global_store_dword %0, %1, off sc0 sc1"
                 :: "v"((u64)p), "v"(v) : "memory");
}
// coalesced 16B write-through store (new in R17: one per thread per publish)
__device__ __forceinline__ void st16Bwt(void* p, u32x4 v) {
    asm volatile("global_store_dwordx4 %0, %1, off sc0 sc1"
                 :: "v"((u64)p), "v"(v) : "memory");
}

// each lane polls its own fp until >= tgt (monotone counters) — R10-proven
__device__ __forceinline__ void poll_all(const uint* fp, uint tgt) {
    for (;;) {
        uint v = __hip_atomic_load(fp, __ATOMIC_RELAXED, __HIP_MEMORY_SCOPE_AGENT);
        if (__all(v >= tgt)) break;
        __builtin_amdgcn_s_sleep(1);
    }
}

// ---------------- prep ----------------
__global__ void k_prep(const float* Wih0, const float* Whh0, const float* Wih1,
                       const float* Whh1, const float* hid, char* ws) {
    ushort* w0  = (ushort*)(ws + OFF_W0B);
    ushort* wh0 = (ushort*)(ws + OFF_WH0B);
    ushort* w1  = (ushort*)(ws + OFF_W1B);
    ushort* wh1 = (ushort*)(ws + OFF_WH1B);
    ushort* hi  = (ushort*)(ws + OFF_HINIT);
    uint*   flg = (uint*)(ws + OFF_FLG);
    const long long total = 524288 + 3 * 1048576 + 131072 + 32768;
    for (long long i = (long long)blockIdx.x * 256 + threadIdx.x; i < total;
         i += (long long)gridDim.x * 256) {
        long long j = i;
        if (j < 524288)  { w0[j]  = f2bf(Wih0[j]); continue; }  j -= 524288;
        if (j < 1048576) { wh0[j] = f2bf(Whh0[j]); continue; }  j -= 1048576;
        if (j < 1048576) { w1[j]  = f2bf(Wih1[j]); continue; }  j -= 1048576;
        if (j < 1048576) { wh1[j] = f2bf(Whh1[j]); continue; }  j -= 1048576;
        if (j < 131072)  { hi[j]  = f2bf(hid[j]);  continue; }  j -= 131072;
        flg[j] = 0u;
    }
}

// ---------------- proj0 ----------------
__launch_bounds__(256)
__global__ void k_proj0(const float* __restrict__ x, const float* __restrict__ bih,
                        const float* __restrict__ bhh, char* ws) {
    const ushort* W = (const ushort*)(ws + OFF_W0B);
    ushort* cbuf = (ushort*)(ws + OFF_BUF);
    int bx = blockIdx.x;
    int mtile = bx >> 2, ntile = bx & 3;
    int tid = threadIdx.x, w = tid >> 6, l = tid & 63;
    int lr = l & 15, lq = l >> 4;
    int arow = mtile * 64 + w * 16 + lr;

    f32x4 acc[16];
#pragma unroll
    for (int i = 0; i < 16; i++) acc[i] = (f32x4){0.f, 0.f, 0.f, 0.f};

    for (int kc = 0; kc < 16; kc++) {
        int k0 = kc * 32 + lq * 8;
        const f32x4* ap = (const f32x4*)(x + (long long)arow * 512 + k0);
        f32x4 a0 = ap[0], a1 = ap[1];
        s16x8 a;
        a[0] = (short)f2bf(a0[0]); a[1] = (short)f2bf(a0[1]);
        a[2] = (short)f2bf(a0[2]); a[3] = (short)f2bf(a0[3]);
        a[4] = (short)f2bf(a1[0]); a[5] = (short)f2bf(a1[1]);
        a[6] = (short)f2bf(a1[2]); a[7] = (short)f2bf(a1[3]);
#pragma unroll
        for (int nf = 0; nf < 16; nf++) {
            int col = ntile * 256 + nf * 16 + lr;
            s16x8 b = *(const s16x8*)(W + (long long)col * 512 + k0);
            acc[nf] = __builtin_amdgcn_mfma_f32_16x16x32_bf16(a, b, acc[nf], 0, 0, 0);
        }
    }
#pragma unroll
    for (int nf = 0; nf < 16; nf++) {
        int col = ntile * 256 + nf * 16 + lr;
        float bb = bih[col] + bhh[col];
#pragma unroll
        for (int j = 0; j < 4; j++) {
            int row = mtile * 64 + w * 16 + lq * 4 + j;
            cbuf[(long long)row * 1024 + col] = f2bf(acc[nf][j] + bb);
        }
    }
}

// ---------------- fused pipeline: L0 | chunked-proj1 | L1 ----------------
// grid 128 x 256.  Identical to R10/R16 except publishes are COALESCED:
// values -> 4KB LDS out-tile -> barrier -> one 16B WT store per thread ->
// barrier (drain) -> lane-0 RELEASE.  (R16 counters: 530KB HBM-write/step vs
// 144KB payload = 3.7x partial-sector amplification from scattered 2-4B WT
// stores; their drain sat on the critical path.)
__launch_bounds__(256, 1)
__global__ void k_recf(const ushort* __restrict__ wh0p, const ushort* __restrict__ wh1p,
                       const ushort* __restrict__ wxp,
                       ushort* __restrict__ cbuf, ushort* __restrict__ hdb1,
                       const ushort* __restrict__ hinitb, uint* __restrict__ flg,
                       float* __restrict__ ring, float* __restrict__ ppart,
                       const float* __restrict__ bih1, const float* __restrict__ bhh1) {
    int wgid = blockIdx.x;
    int x = wgid & 7, hi = wgid >> 3;
    int role, g, s;
    if (x < 4) { g = x; if (hi < 8) { role = 0; s = hi; } else { role = 2; s = hi - 8; } }
    else       { role = 1; g = x - 4; s = hi; }

    int tid = threadIdx.x;
    int l = tid & 63, wv = tid >> 6, lr = l & 15, lq = l >> 4;

    uint* f0g = flg + (g * 8) * 32;            // L0 flags: 8 slots/group
    uint* f1g = flg + 1024 + (g * 8) * 32;     // L1 flags
    uint* fcg = flg + 2048 + (g * 16) * 32;    // proj1 flags

    __shared__ __align__(16) char lds[36864];  // 32KB stage + 4KB out-tile
    ushort* ldsOutH = (ushort*)(lds + 32768);  // [16][128] bf16 (roles 0/2)
    float*  ldsOutF = (float*)(lds + 32768);   // [16][64]  f32  (role 1)

    // weight fragments (B-layout: B[k][col] = W[col][k])
    int colA = (role == 1) ? (s * 64 + wv * 16 + lr) : (s * 128 + wv * 16 + lr);
    int colB = (role == 1) ? colA : (s * 128 + 64 + wv * 16 + lr);
    const ushort* Wb = (role == 0) ? wh0p : (role == 1) ? wxp : wh1p;

    s16x8 wgtA[32], wgtB[32];
#pragma unroll
    for (int kc = 0; kc < 32; kc++)
        wgtA[kc] = *(const s16x8*)(Wb + (long long)colA * 1024 + kc * 32 + lq * 8);
#pragma unroll
    for (int kc = 0; kc < 32; kc++) asm volatile("" : "+v"(wgtA[kc]));
    if (role != 1) {
#pragma unroll
        for (int kc = 0; kc < 32; kc++)
            wgtB[kc] = *(const s16x8*)(Wb + (long long)colB * 1024 + kc * 32 + lq * 8);
#pragma unroll
        for (int kc = 0; kc < 32; kc++) asm volatile("" : "+v"(wgtB[kc]));
    }

    if (role == 1) {
        float bb = bih1[colA] + bhh1[colA];
        uint* myslot = fcg + s * 32;
        for (int k = 0; k < 128; k++) {
            // ---- chunk gate: L0 done through t=8k+7; ring slots free ----
            if (tid < 64) {
                const uint* fp; uint tgt;
                int sl = l & 15;
                if (sl < 8) { fp = f0g + sl * 32; tgt = (uint)(8 * k + 8); }
                else        { fp = f1g + (sl - 8) * 32; tgt = (k >= 2) ? (uint)(8 * k - 8) : 0u; }
                poll_all(fp, tgt);
                if (l == 0)
                    (void)__hip_atomic_load(f0g, __ATOMIC_ACQUIRE, __HIP_MEMORY_SCOPE_AGENT);
            }
            __syncthreads();
            for (int tt = 0; tt < 8; tt++) {
                int t = 8 * k + tt;
                const char* src = (const char*)(cbuf + (t * 64 + g * 16) * 1024);
                u32x4 v[8];
#pragma unroll
                for (int i = 0; i < 8; i++)
                    v[i] = *(const u32x4*)(src + tid * 16 + i * 4096);
                __syncthreads();   // prev GEMM reads + prev out-tile reads done
#pragma unroll
                for (int i = 0; i < 8; i++) {
                    int off = tid * 16 + i * 4096;
                    int row = off >> 11;
                    int sw = (off & 2047) ^ ((row & 7) << 4);
                    *(u32x4*)(lds + row * 2048 + sw) = v[i];
                }
                __syncthreads();
                f32x4 a0c = (f32x4){0.f,0.f,0.f,0.f}, a1c = (f32x4){0.f,0.f,0.f,0.f};
#pragma unroll
                for (int kc = 0; kc < 32; kc += 2) {
                    int b0 = (kc * 64 + lq * 16) ^ ((lr & 7) << 4);
                    int b1 = ((kc + 1) * 64 + lq * 16) ^ ((lr & 7) << 4);
                    s16x8 fA = *(const s16x8*)(lds + lr * 2048 + b0);
                    s16x8 fB = *(const s16x8*)(lds + lr * 2048 + b1);
                    a0c = __builtin_amdgcn_mfma_f32_16x16x32_bf16(fA, wgtA[kc], a0c, 0, 0, 0);
                    a1c = __builtin_amdgcn_mfma_f32_16x16x32_bf16(fB, wgtA[kc + 1], a1c, 0, 0, 0);
                }
                // c1 tile -> LDS [16][64] f32 -> one 16B WT store per thread
#pragma unroll
                for (int j = 0; j < 4; j++)
                    ldsOutF[(lq * 4 + j) * 64 + wv * 16 + lr] = a0c[j] + a1c[j] + bb;
                __syncthreads();
                {
                    float* rd = ring + (long long)((g * 16 + s) * 16 + (t & 15)) * 1024;
                    int row = tid >> 4, co = (tid & 15) * 4;
                    u32x4 vv = *(const u32x4*)(ldsOutF + row * 64 + co);
                    st16Bwt(rd + row * 64 + co, vv);
                }
            }
            __syncthreads();       // drain WT stores (vmcnt) all waves
            if (tid == 0)
                __hip_atomic_store(myslot, (uint)(8 * k + 8), __ATOMIC_RELEASE,
                                   __HIP_MEMORY_SCOPE_AGENT);
        }
        return;
    }

    // ---- roles 0 (L0) and 2 (L1): serial recurrence, 128 cols/WG ----
    uint* myslot = ((role == 0) ? f0g : f1g) + s * 32;
    const ushort* hinit = hinitb + (role == 2 ? 65536 : 0) + g * 16 * 1024;

    for (int t = 0; t < 1024; t++) {
        int cbase = (t * 64 + g * 16) * 1024;

        ushort cfA[4], cfB[4];
        if (role == 0) {
            // prefetch own-col c0[t] (proj0 output, stable) before the gate
#pragma unroll
            for (int j = 0; j < 4; j++) {
                cfA[j] = cbuf[cbase + (lq * 4 + j) * 1024 + colA];
                cfB[j] = cbuf[cbase + (lq * 4 + j) * 1024 + colB];
            }
        }

        // ---- gate ----
        if (tid < 64) {
            if (role == 0) {
                poll_all(f0g + (l & 7) * 32, (uint)t);
            } else {
                const uint* fp; uint tgt;
                int sl = l & 15;
                if (sl < 8) { fp = f1g + sl * 32; tgt = (uint)t; }
                else if (sl < 10) { fp = fcg + (2 * s + (sl - 8)) * 32; tgt = (uint)(t + 1); }
                else { fp = f1g; tgt = (uint)t; }
                poll_all(fp, tgt);
            }
            if (l == 0)
                (void)__hip_atomic_load(f0g, __ATOMIC_ACQUIRE, __HIP_MEMORY_SCOPE_AGENT);
        }
        __syncthreads();

        // ---- c1 ring reads (role 2, after acquire) ----
        float c1A[4], c1B[4];
        if (role == 2) {
            const float* rA = ring + (long long)((g * 16 + 2 * s) * 16 + (t & 15)) * 1024
                            + (wv * 16 + lr);
            const float* rB = ring + (long long)((g * 16 + 2 * s + 1) * 16 + (t & 15)) * 1024
                            + (wv * 16 + lr);
#pragma unroll
            for (int j = 0; j < 4; j++) {
                c1A[j] = rA[(lq * 4 + j) * 64];
                c1B[j] = rB[(lq * 4 + j) * 64];
            }
        }

        // ---- stage h_{t-1} (16 x 1024 bf16) ----
        const char* src;
        if (role == 0)
            src = (const char*)((t == 0) ? hinit
                                         : (cbuf + ((t - 1) * 64 + g * 16) * 1024));
        else
            src = (const char*)((t == 0) ? hinit
                                         : (hdb1 + ((t - 1) & 1) * 65536 + g * 16 * 1024));
#pragma unroll
        for (int i = 0; i < 8; i++) {
            int off = tid * 16 + i * 4096;
            u32x4 v = *(const u32x4*)(src + off);
            int row = off >> 11;
            int sw = (off & 2047) ^ ((row & 7) << 4);
            *(u32x4*)(lds + row * 2048 + sw) = v;
        }
        __syncthreads();

        // ---- GEMM: 64 MFMAs (2 col-fragments), 4 chains ----
        f32x4 aA0 = (f32x4){0.f,0.f,0.f,0.f}, aA1 = (f32x4){0.f,0.f,0.f,0.f};
        f32x4 aB0 = (f32x4){0.f,0.f,0.f,0.f}, aB1 = (f32x4){0.f,0.f,0.f,0.f};
#pragma unroll
        for (int kc = 0; kc < 32; kc += 2) {
            int b0 = (kc * 64 + lq * 16) ^ ((lr & 7) << 4);
            int b1 = ((kc + 1) * 64 + lq * 16) ^ ((lr & 7) << 4);
            s16x8 h0 = *(const s16x8*)(lds + lr * 2048 + b0);
            s16x8 h1 = *(const s16x8*)(lds + lr * 2048 + b1);
            aA0 = __builtin_amdgcn_mfma_f32_16x16x32_bf16(h0, wgtA[kc], aA0, 0, 0, 0);
            aB0 = __builtin_amdgcn_mfma_f32_16x16x32_bf16(h0, wgtB[kc], aB0, 0, 0, 0);
            aA1 = __builtin_amdgcn_mfma_f32_16x16x32_bf16(h1, wgtA[kc + 1], aA1, 0, 0, 0);
            aB1 = __builtin_amdgcn_mfma_f32_16x16x32_bf16(h1, wgtB[kc + 1], aB1, 0, 0, 0);
        }

        float hnA[4], hnB[4];
#pragma unroll
        for (int j = 0; j < 4; j++) {
            float zA = aA0[j] + aA1[j] + (role == 0 ? bf2f(cfA[j]) : c1A[j]);
            float zB = aB0[j] + aB1[j] + (role == 0 ? bf2f(cfB[j]) : c1B[j]);
            zA = fminf(fmaxf(zA, -15.f), 15.f);
            zB = fminf(fmaxf(zB, -15.f), 15.f);
            float eA = __expf(2.f * zA), eB = __expf(2.f * zB);
            hnA[j] = (eA - 1.f) / (eA + 1.f);
            hnB[j] = (eB - 1.f) / (eB + 1.f);
        }

        // ---- publish: LDS out-tile [16][128] bf16 -> one 16B WT store/thread ----
#pragma unroll
        for (int j = 0; j < 4; j++) {
            ldsOutH[(lq * 4 + j) * 128 + wv * 16 + lr]      = f2bf(hnA[j]);
            ldsOutH[(lq * 4 + j) * 128 + 64 + wv * 16 + lr] = f2bf(hnB[j]);
        }
        if (role == 2) {
            float sA = hnA[0] + hnA[1] + hnA[2] + hnA[3];
            float sB = hnB[0] + hnB[1] + hnB[2] + hnB[3];
            sA += __shfl_xor(sA, 16); sA += __shfl_xor(sA, 32);
            sB += __shfl_xor(sB, 16); sB += __shfl_xor(sB, 32);
            if (l < 16) {
                stf32wt(&ppart[(g * 1024 + t) * 1024 + colA], sA);
                stf32wt(&ppart[(g * 1024 + t) * 1024 + colB], sB);
            }
        }
        __syncthreads();   // out-tile complete (also: GEMM LDS reads done)
        {
            int row = tid >> 4, co = (tid & 15) * 8;   // 16B = 8 ushorts
            u32x4 vv = *(const u32x4*)(ldsOutH + row * 128 + co);
            ushort* dst = (role == 0)
                ? (cbuf + cbase + row * 1024 + s * 128 + co)
                : (hdb1 + (t & 1) * 65536 + g * 16 * 1024 + row * 1024 + s * 128 + co);
            st16Bwt(dst, vv);
        }

        __syncthreads();       // each wave drains vmcnt: WT stores complete
        if (tid == 0)
            __hip_atomic_store(myslot, (uint)(t + 1), __ATOMIC_RELEASE,
                               __HIP_MEMORY_SCOPE_AGENT);
    }
}

// ---------------- head ----------------
__launch_bounds__(256)
__global__ void k_head(const float* __restrict__ W1, const float* __restrict__ b1,
                       const float* __restrict__ W2, const float* __restrict__ b2,
                       char* ws, float* __restrict__ out) {
    const float* pp = (const float*)(ws + OFF_PPART);
    int bx = blockIdx.x;
    int t0 = bx * 8;
    int tid = threadIdx.x;

    __shared__ float pl[8][1024];
    __shared__ float red[256][8];

    for (int i = tid; i < 8192; i += 256) {
        int tt = i >> 10, k = i & 1023;
        int base = (t0 + tt) * 1024 + k;
        float s = pp[base] + pp[1048576 + base] + pp[2097152 + base] + pp[3145728 + base];
        pl[tt][k] = s * (1.f / 64.f);
    }
    __syncthreads();

    float po[8];
#pragma unroll
    for (int tt = 0; tt < 8; tt++) po[tt] = 0.f;

    for (int jj = 0; jj < 2; jj++) {
        int j = tid + jj * 256;
        float accv[8];
        float bias = b1[j];
#pragma unroll
        for (int tt = 0; tt < 8; tt++) accv[tt] = bias;
        const float* wr = W1 + (long long)j * 1024;
        for (int k = 0; k < 1024; k += 8) {
            f32x4 wa = *(const f32x4*)(wr + k);
            f32x4 wb = *(const f32x4*)(wr + k + 4);
#pragma unroll
            for (int tt = 0; tt < 8; tt++) {
                accv[tt] += pl[tt][k] * wa[0] + pl[tt][k + 1] * wa[1] +
                            pl[tt][k + 2] * wa[2] + pl[tt][k + 3] * wa[3] +
                            pl[tt][k + 4] * wb[0] + pl[tt][k + 5] * wb[1] +
                            pl[tt][k + 6] * wb[2] + pl[tt][k + 7] * wb[3];
            }
        }
        float w2 = W2[j];
#pragma unroll
        for (int tt = 0; tt < 8; tt++) po[tt] += fmaxf(accv[tt], 0.f) * w2;
    }

#pragma unroll
    for (int tt = 0; tt < 8; tt++) red[tid][tt] = po[tt];
    __syncthreads();
    for (int st = 128; st >= 1; st >>= 1) {
        if (tid < st) {
#pragma unroll
            for (int tt = 0; tt < 8; tt++) red[tid][tt] += red[tid + st][tt];
        }
        __syncthreads();
    }
    if (tid < 8) out[t0 + tid] = 1.f / (1.f + __expf(-(red[0][tid] + b2[0])));
}

extern "C" void kernel_launch(void* const* d_in, const int* in_sizes, int n_in,
                              void* d_out, int out_size, void* d_ws, size_t ws_size,
                              hipStream_t stream) {
    const float* x    = (const float*)d_in[0];
    const float* hid  = (const float*)d_in[1];
    const float* Wih0 = (const float*)d_in[2];
    const float* Whh0 = (const float*)d_in[3];
    const float* bih0 = (const float*)d_in[4];
    const float* bhh0 = (const float*)d_in[5];
    const float* Wih1 = (const float*)d_in[6];
    const float* Whh1 = (const float*)d_in[7];
    const float* bih1 = (const float*)d_in[8];
    const float* bhh1 = (const float*)d_in[9];
    const float* W1   = (const float*)d_in[10];
    const float* b1   = (const float*)d_in[11];
    const float* W2   = (const float*)d_in[12];
    const float* b2   = (const float*)d_in[13];
    char* ws = (char*)d_ws;
    float* out = (float*)d_out;

    hipLaunchKernelGGL(k_prep, dim3(1024), dim3(256), 0, stream,
                       Wih0, Whh0, Wih1, Whh1, hid, ws);
    hipLaunchKernelGGL(k_proj0, dim3(4096), dim3(256), 0, stream, x, bih0, bhh0, ws);
    hipLaunchKernelGGL(k_recf, dim3(128), dim3(256), 0, stream,
                       (const ushort*)(ws + OFF_WH0B), (const ushort*)(ws + OFF_WH1B),
                       (const ushort*)(ws + OFF_W1B),
                       (ushort*)(ws + OFF_BUF), (ushort*)(ws + OFF_HDB1),
                       (const ushort*)(ws + OFF_HINIT), (uint*)(ws + OFF_FLG),
                       (float*)(ws + OFF_RING), (float*)(ws + OFF_PPART),
                       bih1, bhh1);
    hipLaunchKernelGGL(k_head, dim3(128), dim3(256), 0, stream, W1, b1, W2, b2, ws, out);
}

// Round 18
// 6570.576 us; speedup vs baseline: 1.0542x; 1.0542x over previous
//
#include <hip/hip_runtime.h>

typedef unsigned int uint;
typedef unsigned short ushort;
typedef unsigned long long u64;
typedef __attribute__((ext_vector_type(8))) short s16x8;
typedef __attribute__((ext_vector_type(4))) float f32x4;
typedef __attribute__((ext_vector_type(4))) uint u32x4;

// problem dims (fixed)
#define SEQ 1024
#define BATCH 64
#define INDIM 512
#define HID 1024

// ---- workspace layout (bytes) ----
#define OFF_BUF   0ull
#define SZ_BUF    (65536ull * 1024ull * 2ull)           // c0 -> r0 (in-place), bf16
#define OFF_W0B   (OFF_BUF + SZ_BUF)                    // W_ih0 bf16 (1024x512)
#define OFF_WH0B  (OFF_W0B  + 1048576ull)               // W_hh0 bf16
#define OFF_W1B   (OFF_WH0B + 2097152ull)               // W_ih1 bf16
#define OFF_WH1B  (OFF_W1B  + 2097152ull)               // W_hh1 bf16
#define OFF_HINIT (OFF_WH1B + 2097152ull)               // hidden bf16 [2][64][1024]
#define OFF_HDB1  (OFF_HINIT + 262144ull)               // L1 h double buffer [2][64][1024]
#define OFF_FLG   (OFF_HDB1 + 262144ull)                // flag sets, 128B-padded slots
#define OFF_RING  (OFF_FLG + 131072ull)                 // c1 ring [4][16][16][16][64] f32 = 4MB
#define OFF_PPART (OFF_RING + 4194304ull)               // pooled partials [4][1024][1024] f32
#define WS_NEEDED (OFF_PPART + 16777216ull)

__device__ __forceinline__ ushort f2bf(float f) {
    uint u = __float_as_uint(f);
    uint r = (u + 0x7fffu + ((u >> 16) & 1u)) >> 16;
    return (ushort)r;
}
__device__ __forceinline__ float bf2f(ushort h) {
    return __uint_as_float(((uint)h) << 16);
}

// write-through stores (update IF; leave no dirty L2 lines -> release wbl2 cheap)
__device__ __forceinline__ void st16wt(void* p, uint v) {
    asm volatile("global_store_short %0, %1, off sc0 sc1"
                 :: "v"((u64)p), "v"(v) : "memory");
}
__device__ __forceinline__ void stf32wt(float* p, float v) {
    asm volatile("global_store_dword %0, %1, off sc0 sc1"
                 :: "v"((u64)p), "v"(v) : "memory");
}

// each lane polls its own fp until >= tgt (monotone counters)
__device__ __forceinline__ void poll_all(const uint* fp, uint tgt) {
    for (;;) {
        uint v = __hip_atomic_load(fp, __ATOMIC_RELAXED, __HIP_MEMORY_SCOPE_AGENT);
        if (__all(v >= tgt)) break;
        __builtin_amdgcn_s_sleep(1);
    }
}

// ---------------- prep ----------------
__global__ void k_prep(const float* Wih0, const float* Whh0, const float* Wih1,
                       const float* Whh1, const float* hid, char* ws) {
    ushort* w0  = (ushort*)(ws + OFF_W0B);
    ushort* wh0 = (ushort*)(ws + OFF_WH0B);
    ushort* w1  = (ushort*)(ws + OFF_W1B);
    ushort* wh1 = (ushort*)(ws + OFF_WH1B);
    ushort* hi  = (ushort*)(ws + OFF_HINIT);
    uint*   flg = (uint*)(ws + OFF_FLG);
    const long long total = 524288 + 3 * 1048576 + 131072 + 32768;
    for (long long i = (long long)blockIdx.x * 256 + threadIdx.x; i < total;
         i += (long long)gridDim.x * 256) {
        long long j = i;
        if (j < 524288)  { w0[j]  = f2bf(Wih0[j]); continue; }  j -= 524288;
        if (j < 1048576) { wh0[j] = f2bf(Whh0[j]); continue; }  j -= 1048576;
        if (j < 1048576) { w1[j]  = f2bf(Wih1[j]); continue; }  j -= 1048576;
        if (j < 1048576) { wh1[j] = f2bf(Whh1[j]); continue; }  j -= 1048576;
        if (j < 131072)  { hi[j]  = f2bf(hid[j]);  continue; }  j -= 131072;
        flg[j] = 0u;
    }
}

// ---------------- proj0 ----------------
__launch_bounds__(256)
__global__ void k_proj0(const float* __restrict__ x, const float* __restrict__ bih,
                        const float* __restrict__ bhh, char* ws) {
    const ushort* W = (const ushort*)(ws + OFF_W0B);
    ushort* cbuf = (ushort*)(ws + OFF_BUF);
    int bx = blockIdx.x;
    int mtile = bx >> 2, ntile = bx & 3;
    int tid = threadIdx.x, w = tid >> 6, l = tid & 63;
    int lr = l & 15, lq = l >> 4;
    int arow = mtile * 64 + w * 16 + lr;

    f32x4 acc[16];
#pragma unroll
    for (int i = 0; i < 16; i++) acc[i] = (f32x4){0.f, 0.f, 0.f, 0.f};

    for (int kc = 0; kc < 16; kc++) {
        int k0 = kc * 32 + lq * 8;
        const f32x4* ap = (const f32x4*)(x + (long long)arow * 512 + k0);
        f32x4 a0 = ap[0], a1 = ap[1];
        s16x8 a;
        a[0] = (short)f2bf(a0[0]); a[1] = (short)f2bf(a0[1]);
        a[2] = (short)f2bf(a0[2]); a[3] = (short)f2bf(a0[3]);
        a[4] = (short)f2bf(a1[0]); a[5] = (short)f2bf(a1[1]);
        a[6] = (short)f2bf(a1[2]); a[7] = (short)f2bf(a1[3]);
#pragma unroll
        for (int nf = 0; nf < 16; nf++) {
            int col = ntile * 256 + nf * 16 + lr;
            s16x8 b = *(const s16x8*)(W + (long long)col * 512 + k0);
            acc[nf] = __builtin_amdgcn_mfma_f32_16x16x32_bf16(a, b, acc[nf], 0, 0, 0);
        }
    }
#pragma unroll
    for (int nf = 0; nf < 16; nf++) {
        int col = ntile * 256 + nf * 16 + lr;
        float bb = bih[col] + bhh[col];
#pragma unroll
        for (int j = 0; j < 4; j++) {
            int row = mtile * 64 + w * 16 + lq * 4 + j;
            cbuf[(long long)row * 1024 + col] = f2bf(acc[nf][j] + bb);
        }
    }
}

// ---------------- fused pipeline: L0 | chunked-proj1 | L1 ----------------
// grid 128 x 256.  xcd = wgid&7, hi = wgid>>3.
//  xcd<4 : g=xcd;  hi<8 -> role0 (L0, s=hi);  hi>=8 -> role2 (L1, s=hi-8)
//  xcd>=4: role1 (proj1), g=xcd-4, s=hi (0..15)
// Publish: WRITE-THROUGH (sc0 sc1) data stores -> __syncthreads -> lane-0
// RELEASE (wbl2 now ~empty).  Consume: relaxed poll -> lane-0 ACQUIRE
// (buffer_inv drops stale lines) -> __syncthreads -> plain loads.
__launch_bounds__(256, 1)
__global__ void k_recf(const ushort* __restrict__ wh0p, const ushort* __restrict__ wh1p,
                       const ushort* __restrict__ wxp,
                       ushort* __restrict__ cbuf, ushort* __restrict__ hdb1,
                       const ushort* __restrict__ hinitb, uint* __restrict__ flg,
                       float* __restrict__ ring, float* __restrict__ ppart,
                       const float* __restrict__ bih1, const float* __restrict__ bhh1) {
    int wgid = blockIdx.x;
    int x = wgid & 7, hi = wgid >> 3;
    int role, g, s;
    if (x < 4) { g = x; if (hi < 8) { role = 0; s = hi; } else { role = 2; s = hi - 8; } }
    else       { role = 1; g = x - 4; s = hi; }

    int tid = threadIdx.x;
    int l = tid & 63, wv = tid >> 6, lr = l & 15, lq = l >> 4;

    uint* f0g = flg + (g * 8) * 32;            // L0 flags: 8 slots/group
    uint* f1g = flg + 1024 + (g * 8) * 32;     // L1 flags
    uint* fcg = flg + 2048 + (g * 16) * 32;    // proj1 flags

    __shared__ __align__(16) char lds[32768];

    // weight fragments (B-layout: B[k][col] = W[col][k])
    int colA = (role == 1) ? (s * 64 + wv * 16 + lr) : (s * 128 + wv * 16 + lr);
    int colB = (role == 1) ? colA : (s * 128 + 64 + wv * 16 + lr);
    const ushort* Wb = (role == 0) ? wh0p : (role == 1) ? wxp : wh1p;

    s16x8 wgtA[32], wgtB[32];
#pragma unroll
    for (int kc = 0; kc < 32; kc++)
        wgtA[kc] = *(const s16x8*)(Wb + (long long)colA * 1024 + kc * 32 + lq * 8);
#pragma unroll
    for (int kc = 0; kc < 32; kc++) asm volatile("" : "+v"(wgtA[kc]));
    if (role != 1) {
#pragma unroll
        for (int kc = 0; kc < 32; kc++)
            wgtB[kc] = *(const s16x8*)(Wb + (long long)colB * 1024 + kc * 32 + lq * 8);
#pragma unroll
        for (int kc = 0; kc < 32; kc++) asm volatile("" : "+v"(wgtB[kc]));
    }

    if (role == 1) {
        float bb = bih1[colA] + bhh1[colA];
        uint* myslot = fcg + s * 32;
        for (int k = 0; k < 128; k++) {
            // ---- chunk gate: L0 done through t=8k+7; ring slots free ----
            if (tid < 64) {
                const uint* fp; uint tgt;
                int sl = l & 15;
                if (sl < 8) { fp = f0g + sl * 32; tgt = (uint)(8 * k + 8); }
                else        { fp = f1g + (sl - 8) * 32; tgt = (k >= 2) ? (uint)(8 * k - 8) : 0u; }
                poll_all(fp, tgt);
                if (l == 0)
                    (void)__hip_atomic_load(f0g, __ATOMIC_ACQUIRE, __HIP_MEMORY_SCOPE_AGENT);
            }
            __syncthreads();
            for (int tt = 0; tt < 8; tt++) {
                int t = 8 * k + tt;
                const char* src = (const char*)(cbuf + (t * 64 + g * 16) * 1024);
                u32x4 v[8];
#pragma unroll
                for (int i = 0; i < 8; i++)
                    v[i] = *(const u32x4*)(src + tid * 16 + i * 4096);
                __syncthreads();   // prev GEMM reads done before overwrite
#pragma unroll
                for (int i = 0; i < 8; i++) {
                    int off = tid * 16 + i * 4096;
                    int row = off >> 11;
                    int sw = (off & 2047) ^ ((row & 7) << 4);
                    *(u32x4*)(lds + row * 2048 + sw) = v[i];
                }
                __syncthreads();
                f32x4 a0c = (f32x4){0.f,0.f,0.f,0.f}, a1c = (f32x4){0.f,0.f,0.f,0.f};
#pragma unroll
                for (int kc = 0; kc < 32; kc += 2) {
                    int b0 = (kc * 64 + lq * 16) ^ ((lr & 7) << 4);
                    int b1 = ((kc + 1) * 64 + lq * 16) ^ ((lr & 7) << 4);
                    s16x8 fA = *(const s16x8*)(lds + lr * 2048 + b0);
                    s16x8 fB = *(const s16x8*)(lds + lr * 2048 + b1);
                    a0c = __builtin_amdgcn_mfma_f32_16x16x32_bf16(fA, wgtA[kc], a0c, 0, 0, 0);
                    a1c = __builtin_amdgcn_mfma_f32_16x16x32_bf16(fB, wgtA[kc + 1], a1c, 0, 0, 0);
                }
                // write c1 slot (f32, write-through)
                float* rd = ring + (long long)((g * 16 + s) * 16 + (t & 15)) * 1024
                          + (wv * 16 + lr);
#pragma unroll
                for (int j = 0; j < 4; j++)
                    stf32wt(rd + (lq * 4 + j) * 64, a0c[j] + a1c[j] + bb);
            }
            __syncthreads();       // drain write-through stores (vmcnt) all waves
            if (tid == 0)
                __hip_atomic_store(myslot, (uint)(8 * k + 8), __ATOMIC_RELEASE,
                                   __HIP_MEMORY_SCOPE_AGENT);
        }
        return;
    }

    // ---- roles 0 (L0) and 2 (L1): serial recurrence, 128 cols/WG ----
    uint* myslot = ((role == 0) ? f0g : f1g) + s * 32;
    const ushort* hinit = hinitb + (role == 2 ? 65536 : 0) + g * 16 * 1024;

    for (int t = 0; t < 1024; t++) {
        int cbase = (t * 64 + g * 16) * 1024;

        ushort cfA[4], cfB[4];
        if (role == 0) {
            // prefetch own-col c0[t] (proj0 output, stable) before the gate
#pragma unroll
            for (int j = 0; j < 4; j++) {
                cfA[j] = cbuf[cbase + (lq * 4 + j) * 1024 + colA];
                cfB[j] = cbuf[cbase + (lq * 4 + j) * 1024 + colB];
            }
        }

        // ---- gate ----
        if (tid < 64) {
            if (role == 0) {
                poll_all(f0g + (l & 7) * 32, (uint)t);
            } else {
                const uint* fp; uint tgt;
                int sl = l & 15;
                if (sl < 8) { fp = f1g + sl * 32; tgt = (uint)t; }
                else if (sl < 10) { fp = fcg + (2 * s + (sl - 8)) * 32; tgt = (uint)(t + 1); }
                else { fp = f1g; tgt = (uint)t; }
                poll_all(fp, tgt);
            }
            if (l == 0)
                (void)__hip_atomic_load(f0g, __ATOMIC_ACQUIRE, __HIP_MEMORY_SCOPE_AGENT);
        }
        __syncthreads();

        // ---- c1 ring reads (role 2, after acquire) ----
        float c1A[4], c1B[4];
        if (role == 2) {
            const float* rA = ring + (long long)((g * 16 + 2 * s) * 16 + (t & 15)) * 1024
                            + (wv * 16 + lr);
            const float* rB = ring + (long long)((g * 16 + 2 * s + 1) * 16 + (t & 15)) * 1024
                            + (wv * 16 + lr);
#pragma unroll
            for (int j = 0; j < 4; j++) {
                c1A[j] = rA[(lq * 4 + j) * 64];
                c1B[j] = rB[(lq * 4 + j) * 64];
            }
        }

        // ---- stage h_{t-1} (16 x 1024 bf16) ----
        const char* src;
        if (role == 0)
            src = (const char*)((t == 0) ? hinit
                                         : (cbuf + ((t - 1) * 64 + g * 16) * 1024));
        else
            src = (const char*)((t == 0) ? hinit
                                         : (hdb1 + ((t - 1) & 1) * 65536 + g * 16 * 1024));
#pragma unroll
        for (int i = 0; i < 8; i++) {
            int off = tid * 16 + i * 4096;
            u32x4 v = *(const u32x4*)(src + off);
            int row = off >> 11;
            int sw = (off & 2047) ^ ((row & 7) << 4);
            *(u32x4*)(lds + row * 2048 + sw) = v;
        }
        __syncthreads();

        // ---- GEMM: 64 MFMAs (2 col-fragments), 4 chains ----
        f32x4 aA0 = (f32x4){0.f,0.f,0.f,0.f}, aA1 = (f32x4){0.f,0.f,0.f,0.f};
        f32x4 aB0 = (f32x4){0.f,0.f,0.f,0.f}, aB1 = (f32x4){0.f,0.f,0.f,0.f};
#pragma unroll
        for (int kc = 0; kc < 32; kc += 2) {
            int b0 = (kc * 64 + lq * 16) ^ ((lr & 7) << 4);
            int b1 = ((kc + 1) * 64 + lq * 16) ^ ((lr & 7) << 4);
            s16x8 h0 = *(const s16x8*)(lds + lr * 2048 + b0);
            s16x8 h1 = *(const s16x8*)(lds + lr * 2048 + b1);
            aA0 = __builtin_amdgcn_mfma_f32_16x16x32_bf16(h0, wgtA[kc], aA0, 0, 0, 0);
            aB0 = __builtin_amdgcn_mfma_f32_16x16x32_bf16(h0, wgtB[kc], aB0, 0, 0, 0);
            aA1 = __builtin_amdgcn_mfma_f32_16x16x32_bf16(h1, wgtA[kc + 1], aA1, 0, 0, 0);
            aB1 = __builtin_amdgcn_mfma_f32_16x16x32_bf16(h1, wgtB[kc + 1], aB1, 0, 0, 0);
        }

        float hnA[4], hnB[4];
#pragma unroll
        for (int j = 0; j < 4; j++) {
            float zA = aA0[j] + aA1[j] + (role == 0 ? bf2f(cfA[j]) : c1A[j]);
            float zB = aB0[j] + aB1[j] + (role == 0 ? bf2f(cfB[j]) : c1B[j]);
            zA = fminf(fmaxf(zA, -15.f), 15.f);
            zB = fminf(fmaxf(zB, -15.f), 15.f);
            float eA = __expf(2.f * zA), eB = __expf(2.f * zB);
            hnA[j] = (eA - 1.f) / (eA + 1.f);
            hnB[j] = (eB - 1.f) / (eB + 1.f);
        }

        // ---- publish (write-through stores) ----
        if (role == 0) {
#pragma unroll
            for (int j = 0; j < 4; j++) {
                st16wt(cbuf + cbase + (lq * 4 + j) * 1024 + colA, (uint)f2bf(hnA[j]));
                st16wt(cbuf + cbase + (lq * 4 + j) * 1024 + colB, (uint)f2bf(hnB[j]));
            }
        } else {
            ushort* hdst = hdb1 + (t & 1) * 65536 + g * 16 * 1024;
#pragma unroll
            for (int j = 0; j < 4; j++) {
                st16wt(hdst + (lq * 4 + j) * 1024 + colA, (uint)f2bf(hnA[j]));
                st16wt(hdst + (lq * 4 + j) * 1024 + colB, (uint)f2bf(hnB[j]));
            }
            float sA = hnA[0] + hnA[1] + hnA[2] + hnA[3];
            float sB = hnB[0] + hnB[1] + hnB[2] + hnB[3];
            sA += __shfl_xor(sA, 16); sA += __shfl_xor(sA, 32);
            sB += __shfl_xor(sB, 16); sB += __shfl_xor(sB, 32);
            if (l < 16) {
                stf32wt(&ppart[(g * 1024 + t) * 1024 + colA], sA);
                stf32wt(&ppart[(g * 1024 + t) * 1024 + colB], sB);
            }
        }

        __syncthreads();       // each wave drains vmcnt; protects LDS WAR too
        if (tid == 0)
            __hip_atomic_store(myslot, (uint)(t + 1), __ATOMIC_RELEASE,
                               __HIP_MEMORY_SCOPE_AGENT);
    }
}

// ---------------- head ----------------
__launch_bounds__(256)
__global__ void k_head(const float* __restrict__ W1, const float* __restrict__ b1,
                       const float* __restrict__ W2, const float* __restrict__ b2,
                       char* ws, float* __restrict__ out) {
    const float* pp = (const float*)(ws + OFF_PPART);
    int bx = blockIdx.x;
    int t0 = bx * 8;
    int tid = threadIdx.x;

    __shared__ float pl[8][1024];
    __shared__ float red[256][8];

    for (int i = tid; i < 8192; i += 256) {
        int tt = i >> 10, k = i & 1023;
        int base = (t0 + tt) * 1024 + k;
        float s = pp[base] + pp[1048576 + base] + pp[2097152 + base] + pp[3145728 + base];
        pl[tt][k] = s * (1.f / 64.f);
    }
    __syncthreads();

    float po[8];
#pragma unroll
    for (int tt = 0; tt < 8; tt++) po[tt] = 0.f;

    for (int jj = 0; jj < 2; jj++) {
        int j = tid + jj * 256;
        float accv[8];
        float bias = b1[j];
#pragma unroll
        for (int tt = 0; tt < 8; tt++) accv[tt] = bias;
        const float* wr = W1 + (long long)j * 1024;
        for (int k = 0; k < 1024; k += 8) {
            f32x4 wa = *(const f32x4*)(wr + k);
            f32x4 wb = *(const f32x4*)(wr + k + 4);
#pragma unroll
            for (int tt = 0; tt < 8; tt++) {
                accv[tt] += pl[tt][k] * wa[0] + pl[tt][k + 1] * wa[1] +
                            pl[tt][k + 2] * wa[2] + pl[tt][k + 3] * wa[3] +
                            pl[tt][k + 4] * wb[0] + pl[tt][k + 5] * wb[1] +
                            pl[tt][k + 6] * wb[2] + pl[tt][k + 7] * wb[3];
            }
        }
        float w2 = W2[j];
#pragma unroll
        for (int tt = 0; tt < 8; tt++) po[tt] += fmaxf(accv[tt], 0.f) * w2;
    }

#pragma unroll
    for (int tt = 0; tt < 8; tt++) red[tid][tt] = po[tt];
    __syncthreads();
    for (int st = 128; st >= 1; st >>= 1) {
        if (tid < st) {
#pragma unroll
            for (int tt = 0; tt < 8; tt++) red[tid][tt] += red[tid + st][tt];
        }
        __syncthreads();
    }
    if (tid < 8) out[t0 + tid] = 1.f / (1.f + __expf(-(red[0][tid] + b2[0])));
}

extern "C" void kernel_launch(void* const* d_in, const int* in_sizes, int n_in,
                              void* d_out, int out_size, void* d_ws, size_t ws_size,
                              hipStream_t stream) {
    const float* x    = (const float*)d_in[0];
    const float* hid  = (const float*)d_in[1];
    const float* Wih0 = (const float*)d_in[2];
    const float* Whh0 = (const float*)d_in[3];
    const float* bih0 = (const float*)d_in[4];
    const float* bhh0 = (const float*)d_in[5];
    const float* Wih1 = (const float*)d_in[6];
    const float* Whh1 = (const float*)d_in[7];
    const float* bih1 = (const float*)d_in[8];
    const float* bhh1 = (const float*)d_in[9];
    const float* W1   = (const float*)d_in[10];
    const float* b1   = (const float*)d_in[11];
    const float* W2   = (const float*)d_in[12];
    const float* b2   = (const float*)d_in[13];
    char* ws = (char*)d_ws;
    float* out = (float*)d_out;

    hipLaunchKernelGGL(k_prep, dim3(1024), dim3(256), 0, stream,
                       Wih0, Whh0, Wih1, Whh1, hid, ws);
    hipLaunchKernelGGL(k_proj0, dim3(4096), dim3(256), 0, stream, x, bih0, bhh0, ws);
    hipLaunchKernelGGL(k_recf, dim3(128), dim3(256), 0, stream,
                       (const ushort*)(ws + OFF_WH0B), (const ushort*)(ws + OFF_WH1B),
                       (const ushort*)(ws + OFF_W1B),
                       (ushort*)(ws + OFF_BUF), (ushort*)(ws + OFF_HDB1),
                       (const ushort*)(ws + OFF_HINIT), (uint*)(ws + OFF_FLG),
                       (float*)(ws + OFF_RING), (float*)(ws + OFF_PPART),
                       bih1, bhh1);
    hipLaunchKernelGGL(k_head, dim3(128), dim3(256), 0, stream, W1, b1, W2, b2, ws, out);
}